// Round 10
// baseline (630.804 us; speedup 1.0000x reference)
//
#include <hip/hip_runtime.h>

// Problem constants (match reference file)
constexpr int D = 128;       // node feature dim
constexpr int R = 64;        // edge feature dim (in = out)
constexpr int CAP = 64;      // per-dst bucket capacity (in-deg ~ Poisson(16))
constexpr int OVF_CAP = 65536;

typedef float floatx4 __attribute__((ext_vector_type(4)));  // native vec for nontemporal builtins

static __device__ __forceinline__ float4 f4fma(float a, float4 w, float4 c) {
  c.x = fmaf(a, w.x, c.x); c.y = fmaf(a, w.y, c.y);
  c.z = fmaf(a, w.z, c.z); c.w = fmaf(a, w.w, c.w);
  return c;
}

static __device__ __forceinline__ void nt_store4(float4 v, float* p) {
  floatx4 q; q.x = v.x; q.y = v.y; q.z = v.z; q.w = v.w;
  __builtin_nontemporal_store(q, (floatx4*)p);
}

static __device__ __forceinline__ float selk(float4 a, int kk) {
  return (kk == 0) ? a.x : (kk == 1) ? a.y : (kk == 2) ? a.z : a.w;
}

__global__ void k_init(int* deg_out, int* cursor, int* ovf_cnt, int n) {
  int i = blockIdx.x * blockDim.x + threadIdx.x;
  if (i < n) { deg_out[i] = 1; cursor[i] = 0; }  // deg_out=1: self loop
  if (i == 0) ovf_cnt[0] = 0;
}

// merged degree-count + bucket-fill: deg_in recovered as cursor+1 afterwards
__global__ void k_fill(const int* __restrict__ src, const int* __restrict__ dst,
                       int* deg_out, int* cursor, int* bucket,
                       int* ovf_cnt, int2* ovf, int e) {
  int i = blockIdx.x * blockDim.x + threadIdx.x;
  if (i >= e) return;
  int d = dst[i], s = src[i];
  atomicAdd(&deg_out[s], 1);
  int slot = atomicAdd(&cursor[d], 1);
  if (slot < CAP) bucket[(size_t)d * CAP + slot] = s;
  else {
    int oi = atomicAdd(ovf_cnt, 1);
    if (oi < OVF_CAP) ovf[oi] = make_int2(s, d);
  }
}

__global__ void k_norm(const int* __restrict__ deg_out, const int* __restrict__ cursor,
                       float* ns, float* nd, int n) {
  int i = blockIdx.x * blockDim.x + threadIdx.x;
  if (i < n) {
    ns[i] = rsqrtf((float)deg_out[i]);
    nd[i] = rsqrtf((float)(cursor[i] + 1));   // +1 = self loop
  }
}

// One 32-lane group per node; each lane holds a float4 (D=128 = 32*4).
// ns != null (layer1): agg[v] = x[v]*ns[v] + sum x[s]*ns[s]
// ns == null (layer2): input is pre-scaled h1' = h1*ns, so agg[v] = h'[v] + sum h'[s]
__global__ __launch_bounds__(256) void k_agg(const float* __restrict__ X,
                                             const float* __restrict__ ns,
                                             const int* __restrict__ cursor,
                                             const int* __restrict__ bucket,
                                             float* __restrict__ agg, int n) {
  int g = threadIdx.x >> 5, lane = threadIdx.x & 31;
  int v = blockIdx.x * 8 + g;
  if (v >= n) return;
  float4 acc;
  int cnt = min(cursor[v], CAP);
  const int* bk = bucket + (size_t)v * CAP;
  if (ns) {
    float4 xv = ((const float4*)(X + (size_t)v * D))[lane];
    float s = ns[v];
    acc.x = xv.x * s; acc.y = xv.y * s; acc.z = xv.z * s; acc.w = xv.w * s;
    int i = 0;
    for (; i + 4 <= cnt; i += 4) {
      int s0 = bk[i], s1 = bk[i + 1], s2 = bk[i + 2], s3 = bk[i + 3];
      float n0 = ns[s0], n1 = ns[s1], n2 = ns[s2], n3 = ns[s3];
      float4 x0 = ((const float4*)(X + (size_t)s0 * D))[lane];
      float4 x1 = ((const float4*)(X + (size_t)s1 * D))[lane];
      float4 x2 = ((const float4*)(X + (size_t)s2 * D))[lane];
      float4 x3 = ((const float4*)(X + (size_t)s3 * D))[lane];
      acc = f4fma(n0, x0, acc); acc = f4fma(n1, x1, acc);
      acc = f4fma(n2, x2, acc); acc = f4fma(n3, x3, acc);
    }
    for (; i < cnt; ++i) {
      int s0 = bk[i];
      float4 x0 = ((const float4*)(X + (size_t)s0 * D))[lane];
      acc = f4fma(ns[s0], x0, acc);
    }
  } else {
    acc = ((const float4*)(X + (size_t)v * D))[lane];
    int i = 0;
    for (; i + 4 <= cnt; i += 4) {
      int s0 = bk[i], s1 = bk[i + 1], s2 = bk[i + 2], s3 = bk[i + 3];
      float4 x0 = ((const float4*)(X + (size_t)s0 * D))[lane];
      float4 x1 = ((const float4*)(X + (size_t)s1 * D))[lane];
      float4 x2 = ((const float4*)(X + (size_t)s2 * D))[lane];
      float4 x3 = ((const float4*)(X + (size_t)s3 * D))[lane];
      acc.x += x0.x + x1.x + x2.x + x3.x;
      acc.y += x0.y + x1.y + x2.y + x3.y;
      acc.z += x0.z + x1.z + x2.z + x3.z;
      acc.w += x0.w + x1.w + x2.w + x3.w;
    }
    for (; i < cnt; ++i) {
      int s0 = bk[i];
      float4 x0 = ((const float4*)(X + (size_t)s0 * D))[lane];
      acc.x += x0.x; acc.y += x0.y; acc.z += x0.z; acc.w += x0.w;
    }
  }
  ((float4*)(agg + (size_t)v * D))[lane] = acc;
}

// Rare overflow edges (slot >= CAP): f32 atomics, normally zero work.
__global__ __launch_bounds__(128) void k_ovf(const float* __restrict__ X,
                                             const float* __restrict__ ns,
                                             const int* __restrict__ ovf_cnt,
                                             const int2* __restrict__ ovf,
                                             float* agg) {
  int m = min(ovf_cnt[0], OVF_CAP);
  int t = threadIdx.x;
  for (int i = blockIdx.x; i < m; i += gridDim.x) {
    int2 e = ovf[i];
    float s = ns ? ns[e.x] : 1.f;
    atomicAdd(&agg[(size_t)e.y * D + t], X[(size_t)e.x * D + t] * s);
  }
}

// out[r] = relu( (agg[r] @ W)*nd[r] + b ) * (post ? post[r] : 1). 64-row tile per block.
// post-scale folds next layer's norm_src into this epilogue (valid: post > 0).
__global__ __launch_bounds__(256) void k_gemm_relu(const float* __restrict__ A,
                                                   const float* __restrict__ ndv,
                                                   const float* __restrict__ W,
                                                   const float* __restrict__ bias,
                                                   const float* __restrict__ post,
                                                   float* __restrict__ out, int n) {
  __shared__ float Wl[D * D];  // 64 KiB
  int t = threadIdx.x;
  for (int i = t; i < (D * D) / 4; i += 256) ((float4*)Wl)[i] = ((const float4*)W)[i];
  __syncthreads();

  int ct = t & 15, rg = t >> 4;
  int c0 = ct << 2;            // cols c0..c0+3 and c0+64..c0+67
  int row0 = blockIdx.x * 64;

  float4 bb0 = *(const float4*)(bias + c0);
  float4 bb1 = *(const float4*)(bias + c0 + 64);

  int r[4]; const float4* Ap[4];
#pragma unroll
  for (int m = 0; m < 4; ++m) {
    r[m] = row0 + rg + 16 * m;
    int rc = (r[m] < n) ? r[m] : (n - 1);
    Ap[m] = (const float4*)(A + (size_t)rc * D);
  }

  float4 acc[4][2];
#pragma unroll
  for (int m = 0; m < 4; ++m) {
    acc[m][0] = make_float4(0.f, 0.f, 0.f, 0.f);
    acc[m][1] = make_float4(0.f, 0.f, 0.f, 0.f);
  }

#pragma unroll 8
  for (int k4 = 0; k4 < 32; ++k4) {
    float4 a0 = Ap[0][k4], a1 = Ap[1][k4], a2 = Ap[2][k4], a3 = Ap[3][k4];
    const float* wbase = Wl + (k4 << 9) + c0;
#pragma unroll
    for (int kk = 0; kk < 4; ++kk) {
      float4 w0 = *(const float4*)(wbase + (kk << 7));
      float4 w1 = *(const float4*)(wbase + (kk << 7) + 64);
      float e0 = selk(a0, kk), e1 = selk(a1, kk), e2 = selk(a2, kk), e3 = selk(a3, kk);
      acc[0][0] = f4fma(e0, w0, acc[0][0]); acc[0][1] = f4fma(e0, w1, acc[0][1]);
      acc[1][0] = f4fma(e1, w0, acc[1][0]); acc[1][1] = f4fma(e1, w1, acc[1][1]);
      acc[2][0] = f4fma(e2, w0, acc[2][0]); acc[2][1] = f4fma(e2, w1, acc[2][1]);
      acc[3][0] = f4fma(e3, w0, acc[3][0]); acc[3][1] = f4fma(e3, w1, acc[3][1]);
    }
  }

#pragma unroll
  for (int m = 0; m < 4; ++m) {
    if (r[m] < n) {
      float ndr = ndv[r[m]];
      float ps = post ? post[r[m]] : 1.f;
      float4 o0, o1;
      o0.x = fmaxf(fmaf(acc[m][0].x, ndr, bb0.x), 0.f) * ps;
      o0.y = fmaxf(fmaf(acc[m][0].y, ndr, bb0.y), 0.f) * ps;
      o0.z = fmaxf(fmaf(acc[m][0].z, ndr, bb0.z), 0.f) * ps;
      o0.w = fmaxf(fmaf(acc[m][0].w, ndr, bb0.w), 0.f) * ps;
      o1.x = fmaxf(fmaf(acc[m][1].x, ndr, bb1.x), 0.f) * ps;
      o1.y = fmaxf(fmaf(acc[m][1].y, ndr, bb1.y), 0.f) * ps;
      o1.z = fmaxf(fmaf(acc[m][1].z, ndr, bb1.z), 0.f) * ps;
      o1.w = fmaxf(fmaf(acc[m][1].w, ndr, bb1.w), 0.f) * ps;
      *(float4*)(out + (size_t)r[m] * D + c0) = o0;
      *(float4*)(out + (size_t)r[m] * D + c0 + 64) = o1;
    }
  }
}

// e_h rows [0,E): text_h[row] @ relW + relb ; rows [E,E+N): relb (zero text).
// v7: NO LDS for A. Thread (rg,ct) reads its 8 rows straight from global:
// the 16 ct-threads sharing a row are in the SAME wave instruction -> HW
// broadcast; each 16B of T requested once, 64B-line reuse within k4 window.
// LDS holds only W (16KB, 2-way-free b128 reads). 128 rows/block, 8 rows x
// 4 cols/thread: W-LDS ~24cyc/row, VALU 44us, VGPR ~70 -> 6+ blocks/CU.
__global__ __launch_bounds__(256) void k_rel(const float* __restrict__ T,
                                             const float* __restrict__ Wr,
                                             const float* __restrict__ br,
                                             float* __restrict__ out,
                                             int e, int ntot) {
  __shared__ float Wl[R * R];      // 16 KiB
  int t = threadIdx.x;
  for (int i = t; i < (R * R) / 4; i += 256) ((float4*)Wl)[i] = ((const float4*)Wr)[i];
  __syncthreads();

  int ct = t & 15, rg = t >> 4;    // 16 cts x 4 cols = 64 cols; 16 rgs x 8 rows = 128 rows
  int c0 = ct << 2;
  int base = blockIdx.x * 128;
  float4 bb = *(const float4*)(br + c0);
  const float4 z4 = make_float4(0.f, 0.f, 0.f, 0.f);

  float4 acc[8];
#pragma unroll
  for (int m = 0; m < 8; ++m) acc[m] = bb;

  int row[8];
#pragma unroll
  for (int m = 0; m < 8; ++m) row[m] = base + rg + 16 * m;

  if (base + 127 < e) {
    // fast path: whole tile in-range (99.97% of blocks)
    const float4* Ap[8];
#pragma unroll
    for (int m = 0; m < 8; ++m) Ap[m] = (const float4*)(T + (size_t)row[m] * R);
#pragma unroll 4
    for (int k4 = 0; k4 < 16; ++k4) {
      float4 a[8];
#pragma unroll
      for (int m = 0; m < 8; ++m) a[m] = Ap[m][k4];
#pragma unroll
      for (int kk = 0; kk < 4; ++kk) {
        float4 w = *(const float4*)(Wl + (((k4 << 2) + kk) << 6) + c0);
#pragma unroll
        for (int m = 0; m < 8; ++m) acc[m] = f4fma(selk(a[m], kk), w, acc[m]);
      }
    }
  } else {
    // boundary blocks: predicated loads (rows >= e contribute zero)
    const float4* Ap[8]; bool vld[8];
#pragma unroll
    for (int m = 0; m < 8; ++m) {
      vld[m] = row[m] < e;
      Ap[m] = (const float4*)(T + (size_t)(vld[m] ? row[m] : 0) * R);
    }
#pragma unroll 4
    for (int k4 = 0; k4 < 16; ++k4) {
      float4 a[8];
#pragma unroll
      for (int m = 0; m < 8; ++m) a[m] = vld[m] ? Ap[m][k4] : z4;
#pragma unroll
      for (int kk = 0; kk < 4; ++kk) {
        float4 w = *(const float4*)(Wl + (((k4 << 2) + kk) << 6) + c0);
#pragma unroll
        for (int m = 0; m < 8; ++m) acc[m] = f4fma(selk(a[m], kk), w, acc[m]);
      }
    }
  }

#pragma unroll
  for (int m = 0; m < 8; ++m)
    if (row[m] < ntot) nt_store4(acc[m], out + (size_t)row[m] * R + c0);
}

extern "C" void kernel_launch(void* const* d_in, const int* in_sizes, int n_in,
                              void* d_out, int out_size, void* d_ws, size_t ws_size,
                              hipStream_t stream) {
  const int*   src  = (const int*)d_in[0];
  const int*   dst  = (const int*)d_in[1];
  const float* x    = (const float*)d_in[2];
  const float* text = (const float*)d_in[3];
  const float* W1   = (const float*)d_in[4];
  const float* b1   = (const float*)d_in[5];
  const float* W2   = (const float*)d_in[6];
  const float* b2   = (const float*)d_in[7];
  const float* relW = (const float*)d_in[8];
  const float* relb = (const float*)d_in[9];

  const int E = in_sizes[0];
  const int N = in_sizes[2] / D;

  float* outH = (float*)d_out;
  float* outE = outH + (size_t)N * D;

  // workspace carve-out (256B aligned)
  char* w = (char*)d_ws;
  auto alloc = [&](size_t bytes) -> void* {
    void* p = (void*)w;
    w += (bytes + 255) & ~(size_t)255;
    return p;
  };
  int*   deg_out  = (int*)alloc((size_t)N * 4);
  int*   cursor   = (int*)alloc((size_t)N * 4);
  float* norm_src = (float*)alloc((size_t)N * 4);
  float* norm_dst = (float*)alloc((size_t)N * 4);
  int*   ovf_cnt  = (int*)alloc(256);
  int2*  ovf      = (int2*)alloc((size_t)OVF_CAP * 8);
  int*   bucket   = (int*)alloc((size_t)N * CAP * 4);
  float* agg      = (float*)alloc((size_t)N * D * 4);

  int nbN = (N + 255) / 256;
  int nbE = (E + 255) / 256;

  k_init<<<nbN, 256, 0, stream>>>(deg_out, cursor, ovf_cnt, N);
  k_fill<<<nbE, 256, 0, stream>>>(src, dst, deg_out, cursor, bucket, ovf_cnt, ovf, E);
  k_norm<<<nbN, 256, 0, stream>>>(deg_out, cursor, norm_src, norm_dst, N);

  // layer 1: h1' = relu((agg1@W1)*nd + b1) * ns  -> outH   (ns folded for layer-2 gather)
  k_agg<<<(N + 7) / 8, 256, 0, stream>>>(x, norm_src, cursor, bucket, agg, N);
  k_ovf<<<64, 128, 0, stream>>>(x, norm_src, ovf_cnt, ovf, agg);
  k_gemm_relu<<<(N + 63) / 64, 256, 0, stream>>>(agg, norm_dst, W1, b1, norm_src, outH, N);

  // layer 2: gather pre-scaled h1' (no ns), h2 = relu((agg2@W2)*nd + b2) -> outH
  k_agg<<<(N + 7) / 8, 256, 0, stream>>>(outH, nullptr, cursor, bucket, agg, N);
  k_ovf<<<64, 128, 0, stream>>>(outH, nullptr, ovf_cnt, ovf, agg);
  k_gemm_relu<<<(N + 63) / 64, 256, 0, stream>>>(agg, norm_dst, W2, b2, nullptr, outH, N);

  // edge features
  int ntot = E + N;
  int nTiles = (ntot + 127) / 128;
  k_rel<<<nTiles, 256, 0, stream>>>(text, relW, relb, outE, E, ntot);
}

// Round 11
// 372.424 us; speedup vs baseline: 1.6938x; 1.6938x over previous
//
#include <hip/hip_runtime.h>

// Problem constants (match reference file)
constexpr int D = 128;       // node feature dim
constexpr int R = 64;        // edge feature dim (in = out)
constexpr int CAP = 64;      // per-dst bucket capacity (in-deg ~ Poisson(16))
constexpr int OVF_CAP = 65536;
constexpr int TPAD = 68;     // padded T-tile row stride: A banks 4*rg+4*k4 -> conflict-free

typedef float floatx4 __attribute__((ext_vector_type(4)));  // native vec for nontemporal builtins

static __device__ __forceinline__ float4 f4fma(float a, float4 w, float4 c) {
  c.x = fmaf(a, w.x, c.x); c.y = fmaf(a, w.y, c.y);
  c.z = fmaf(a, w.z, c.z); c.w = fmaf(a, w.w, c.w);
  return c;
}

static __device__ __forceinline__ void nt_store4(float4 v, float* p) {
  floatx4 q; q.x = v.x; q.y = v.y; q.z = v.z; q.w = v.w;
  __builtin_nontemporal_store(q, (floatx4*)p);
}

static __device__ __forceinline__ float selk(float4 a, int kk) {
  return (kk == 0) ? a.x : (kk == 1) ? a.y : (kk == 2) ? a.z : a.w;
}

// ---- bf16 pack/unpack (RNE). uint holds 2 bf16: lo = even d, hi = odd d ----
static __device__ __forceinline__ unsigned pack_bf16x2(float lo, float hi) {
  unsigned ulo = __float_as_uint(lo), uhi = __float_as_uint(hi);
  ulo += 0x7FFFu + ((ulo >> 16) & 1u);
  uhi += 0x7FFFu + ((uhi >> 16) & 1u);
  return (ulo >> 16) | (uhi & 0xFFFF0000u);
}
static __device__ __forceinline__ float bf_lo(unsigned u) { return __uint_as_float(u << 16); }
static __device__ __forceinline__ float bf_hi(unsigned u) { return __uint_as_float(u & 0xFFFF0000u); }

__global__ void k_init(int* deg_out, int* cursor, int* ovf_cnt, int n) {
  int i = blockIdx.x * blockDim.x + threadIdx.x;
  if (i < n) { deg_out[i] = 1; cursor[i] = 0; }  // deg_out=1: self loop
  if (i == 0) ovf_cnt[0] = 0;
}

// merged degree-count + bucket-fill: deg_in recovered as cursor+1 afterwards
__global__ void k_fill(const int* __restrict__ src, const int* __restrict__ dst,
                       int* deg_out, int* cursor, int* bucket,
                       int* ovf_cnt, int2* ovf, int e) {
  int i = blockIdx.x * blockDim.x + threadIdx.x;
  if (i >= e) return;
  int d = dst[i], s = src[i];
  atomicAdd(&deg_out[s], 1);
  int slot = atomicAdd(&cursor[d], 1);
  if (slot < CAP) bucket[(size_t)d * CAP + slot] = s;
  else {
    int oi = atomicAdd(ovf_cnt, 1);
    if (oi < OVF_CAP) ovf[oi] = make_int2(s, d);
  }
}

__global__ void k_norm(const int* __restrict__ deg_out, const int* __restrict__ cursor,
                       float* ns, float* nd, int n) {
  int i = blockIdx.x * blockDim.x + threadIdx.x;
  if (i < n) {
    ns[i] = rsqrtf((float)deg_out[i]);
    nd[i] = rsqrtf((float)(cursor[i] + 1));   // +1 = self loop
  }
}

// xs[v][d] = bf16( x[v][d] * ns[v] ).  One thread = 8 floats -> uint4.
__global__ __launch_bounds__(256) void k_prep(const float* __restrict__ X,
                                              const float* __restrict__ ns,
                                              uint4* __restrict__ xs, int n16) {
  int idx = blockIdx.x * 256 + threadIdx.x;
  if (idx >= n16) return;
  int row = idx >> 4, g = idx & 15;
  const float4* xp = (const float4*)(X + (size_t)row * D + g * 8);
  float4 a = xp[0], b = xp[1];
  float s = ns[row];
  uint4 o;
  o.x = pack_bf16x2(a.x * s, a.y * s);
  o.y = pack_bf16x2(a.z * s, a.w * s);
  o.z = pack_bf16x2(b.x * s, b.y * s);
  o.w = pack_bf16x2(b.z * s, b.w * s);
  xs[(size_t)row * 16 + g] = o;
}

// bf16 gather-aggregate (norms pre-folded into XS).
// agg[v] = XS[v] + sum_{(s->v)} XS[s], f32 accum. 32 lanes/node, uint2/lane.
__global__ __launch_bounds__(256) void k_agg_b(const unsigned* __restrict__ XS,
                                               const int* __restrict__ cursor,
                                               const int* __restrict__ bucket,
                                               float* __restrict__ agg, int n) {
  int g = threadIdx.x >> 5, lane = threadIdx.x & 31;
  int v = blockIdx.x * 8 + g;
  if (v >= n) return;
  float4 acc;
  {
    uint2 u = ((const uint2*)(XS + (size_t)v * 64))[lane];
    acc.x = bf_lo(u.x); acc.y = bf_hi(u.x); acc.z = bf_lo(u.y); acc.w = bf_hi(u.y);
  }
  int cnt = min(cursor[v], CAP);
  const int* bk = bucket + (size_t)v * CAP;
  int i = 0;
  for (; i + 4 <= cnt; i += 4) {
    int s0 = bk[i], s1 = bk[i + 1], s2 = bk[i + 2], s3 = bk[i + 3];
    uint2 u0 = ((const uint2*)(XS + (size_t)s0 * 64))[lane];
    uint2 u1 = ((const uint2*)(XS + (size_t)s1 * 64))[lane];
    uint2 u2 = ((const uint2*)(XS + (size_t)s2 * 64))[lane];
    uint2 u3 = ((const uint2*)(XS + (size_t)s3 * 64))[lane];
    acc.x += bf_lo(u0.x) + bf_lo(u1.x) + bf_lo(u2.x) + bf_lo(u3.x);
    acc.y += bf_hi(u0.x) + bf_hi(u1.x) + bf_hi(u2.x) + bf_hi(u3.x);
    acc.z += bf_lo(u0.y) + bf_lo(u1.y) + bf_lo(u2.y) + bf_lo(u3.y);
    acc.w += bf_hi(u0.y) + bf_hi(u1.y) + bf_hi(u2.y) + bf_hi(u3.y);
  }
  for (; i < cnt; ++i) {
    int s0 = bk[i];
    uint2 u0 = ((const uint2*)(XS + (size_t)s0 * 64))[lane];
    acc.x += bf_lo(u0.x); acc.y += bf_hi(u0.x);
    acc.z += bf_lo(u0.y); acc.w += bf_hi(u0.y);
  }
  ((float4*)(agg + (size_t)v * D))[lane] = acc;
}

// Rare overflow edges (slot >= CAP): f32 atomics from bf16 source, normally zero work.
__global__ __launch_bounds__(128) void k_ovf_b(const unsigned* __restrict__ XS,
                                               const int* __restrict__ ovf_cnt,
                                               const int2* __restrict__ ovf,
                                               float* agg) {
  int m = min(ovf_cnt[0], OVF_CAP);
  int t = threadIdx.x;
  for (int i = blockIdx.x; i < m; i += gridDim.x) {
    int2 e = ovf[i];
    unsigned u = XS[(size_t)e.x * 64 + (t >> 1)];
    float f = (t & 1) ? bf_hi(u) : bf_lo(u);
    atomicAdd(&agg[(size_t)e.y * D + t], f);
  }
}

// z = agg[r] @ W; o = relu(z*nd[r] + b).
// bf16out: store bf16(o * post[r]) to outb (layer 1, post=ns) ; else f32 o to outf.
__global__ __launch_bounds__(256) void k_gemm_relu(const float* __restrict__ A,
                                                   const float* __restrict__ ndv,
                                                   const float* __restrict__ W,
                                                   const float* __restrict__ bias,
                                                   const float* __restrict__ post,
                                                   float* __restrict__ outf,
                                                   unsigned* __restrict__ outb,
                                                   int n) {
  __shared__ float Wl[D * D];  // 64 KiB
  int t = threadIdx.x;
  for (int i = t; i < (D * D) / 4; i += 256) ((float4*)Wl)[i] = ((const float4*)W)[i];
  __syncthreads();

  int ct = t & 15, rg = t >> 4;
  int c0 = ct << 2;            // cols c0..c0+3 and c0+64..c0+67
  int row0 = blockIdx.x * 64;

  float4 bb0 = *(const float4*)(bias + c0);
  float4 bb1 = *(const float4*)(bias + c0 + 64);

  int r[4]; const float4* Ap[4];
#pragma unroll
  for (int m = 0; m < 4; ++m) {
    r[m] = row0 + rg + 16 * m;
    int rc = (r[m] < n) ? r[m] : (n - 1);
    Ap[m] = (const float4*)(A + (size_t)rc * D);
  }

  float4 acc[4][2];
#pragma unroll
  for (int m = 0; m < 4; ++m) {
    acc[m][0] = make_float4(0.f, 0.f, 0.f, 0.f);
    acc[m][1] = make_float4(0.f, 0.f, 0.f, 0.f);
  }

#pragma unroll 8
  for (int k4 = 0; k4 < 32; ++k4) {
    float4 a0 = Ap[0][k4], a1 = Ap[1][k4], a2 = Ap[2][k4], a3 = Ap[3][k4];
    const float* wbase = Wl + (k4 << 9) + c0;
#pragma unroll
    for (int kk = 0; kk < 4; ++kk) {
      float4 w0 = *(const float4*)(wbase + (kk << 7));
      float4 w1 = *(const float4*)(wbase + (kk << 7) + 64);
      float e0 = selk(a0, kk), e1 = selk(a1, kk), e2 = selk(a2, kk), e3 = selk(a3, kk);
      acc[0][0] = f4fma(e0, w0, acc[0][0]); acc[0][1] = f4fma(e0, w1, acc[0][1]);
      acc[1][0] = f4fma(e1, w0, acc[1][0]); acc[1][1] = f4fma(e1, w1, acc[1][1]);
      acc[2][0] = f4fma(e2, w0, acc[2][0]); acc[2][1] = f4fma(e2, w1, acc[2][1]);
      acc[3][0] = f4fma(e3, w0, acc[3][0]); acc[3][1] = f4fma(e3, w1, acc[3][1]);
    }
  }

#pragma unroll
  for (int m = 0; m < 4; ++m) {
    if (r[m] < n) {
      float ndr = ndv[r[m]];
      float4 o0, o1;
      o0.x = fmaxf(fmaf(acc[m][0].x, ndr, bb0.x), 0.f);
      o0.y = fmaxf(fmaf(acc[m][0].y, ndr, bb0.y), 0.f);
      o0.z = fmaxf(fmaf(acc[m][0].z, ndr, bb0.z), 0.f);
      o0.w = fmaxf(fmaf(acc[m][0].w, ndr, bb0.w), 0.f);
      o1.x = fmaxf(fmaf(acc[m][1].x, ndr, bb1.x), 0.f);
      o1.y = fmaxf(fmaf(acc[m][1].y, ndr, bb1.y), 0.f);
      o1.z = fmaxf(fmaf(acc[m][1].z, ndr, bb1.z), 0.f);
      o1.w = fmaxf(fmaf(acc[m][1].w, ndr, bb1.w), 0.f);
      if (outb) {
        float ps = post[r[m]];
        uint2 p0, p1;
        p0.x = pack_bf16x2(o0.x * ps, o0.y * ps);
        p0.y = pack_bf16x2(o0.z * ps, o0.w * ps);
        p1.x = pack_bf16x2(o1.x * ps, o1.y * ps);
        p1.y = pack_bf16x2(o1.z * ps, o1.w * ps);
        *(uint2*)(outb + (size_t)r[m] * 64 + (c0 >> 1)) = p0;
        *(uint2*)(outb + (size_t)r[m] * 64 + (c0 >> 1) + 32) = p1;
      } else {
        *(float4*)(outf + (size_t)r[m] * D + c0) = o0;
        *(float4*)(outf + (size_t)r[m] * D + c0 + 64) = o1;
      }
    }
  }
}

// e_h rows [0,E): text_h[row] @ relW + relb ; rows [E,E+N): relb (zero text).
// v5 (R8-proven 153us): one 64-row tile/block, dispatch order; T loads first
// (hide under W staging); LDS 33.8KB -> 4 blocks/CU, occ ~42%; nt stores.
__global__ __launch_bounds__(256) void k_rel(const float* __restrict__ T,
                                             const float* __restrict__ Wr,
                                             const float* __restrict__ br,
                                             float* __restrict__ out,
                                             int e, int ntot) {
  __shared__ float Wl[R * R];      // 16 KiB
  __shared__ float Tl[64 * TPAD];  // 17 KiB
  int t = threadIdx.x;
  int tile = blockIdx.x;
  const float4 z4 = make_float4(0.f, 0.f, 0.f, 0.f);

  // issue T-tile loads first: 4 coalesced float4 loads per thread
  float4 pre[4];
#pragma unroll
  for (int j = 0; j < 4; ++j) {
    int q = t + 256 * j, rr = q >> 4, c4 = q & 15;
    int grow = tile * 64 + rr;
    pre[j] = (grow < e) ? ((const float4*)T)[(size_t)grow * 16 + c4] : z4;
  }
  // W staging overlaps the T loads in flight
  for (int i = t; i < (R * R) / 4; i += 256) ((float4*)Wl)[i] = ((const float4*)Wr)[i];
#pragma unroll
  for (int j = 0; j < 4; ++j) {
    int q = t + 256 * j, rr = q >> 4, c4 = q & 15;
    *(float4*)&Tl[rr * TPAD + (c4 << 2)] = pre[j];
  }
  __syncthreads();

  int ct = t & 15, rg = t >> 4;
  int c0 = ct << 2;
  float4 bb = *(const float4*)(br + c0);

  float4 acc0 = bb, acc1 = bb, acc2 = bb, acc3 = bb;
#pragma unroll 4
  for (int k4 = 0; k4 < 16; ++k4) {
    float4 a0 = *(const float4*)&Tl[(rg     ) * TPAD + (k4 << 2)];
    float4 a1 = *(const float4*)&Tl[(rg + 16) * TPAD + (k4 << 2)];
    float4 a2 = *(const float4*)&Tl[(rg + 32) * TPAD + (k4 << 2)];
    float4 a3 = *(const float4*)&Tl[(rg + 48) * TPAD + (k4 << 2)];
    const float* wbase = Wl + (k4 << 8) + c0;
#pragma unroll
    for (int kk = 0; kk < 4; ++kk) {
      float4 w = *(const float4*)(wbase + (kk << 6));
      float e0 = selk(a0, kk), e1 = selk(a1, kk), e2 = selk(a2, kk), e3 = selk(a3, kk);
      acc0 = f4fma(e0, w, acc0);
      acc1 = f4fma(e1, w, acc1);
      acc2 = f4fma(e2, w, acc2);
      acc3 = f4fma(e3, w, acc3);
    }
  }

  int base = tile * 64;
  if (base + rg      < ntot) nt_store4(acc0, out + (size_t)(base + rg     ) * R + c0);
  if (base + rg + 16 < ntot) nt_store4(acc1, out + (size_t)(base + rg + 16) * R + c0);
  if (base + rg + 32 < ntot) nt_store4(acc2, out + (size_t)(base + rg + 32) * R + c0);
  if (base + rg + 48 < ntot) nt_store4(acc3, out + (size_t)(base + rg + 48) * R + c0);
}

extern "C" void kernel_launch(void* const* d_in, const int* in_sizes, int n_in,
                              void* d_out, int out_size, void* d_ws, size_t ws_size,
                              hipStream_t stream) {
  const int*   src  = (const int*)d_in[0];
  const int*   dst  = (const int*)d_in[1];
  const float* x    = (const float*)d_in[2];
  const float* text = (const float*)d_in[3];
  const float* W1   = (const float*)d_in[4];
  const float* b1   = (const float*)d_in[5];
  const float* W2   = (const float*)d_in[6];
  const float* b2   = (const float*)d_in[7];
  const float* relW = (const float*)d_in[8];
  const float* relb = (const float*)d_in[9];

  const int E = in_sizes[0];
  const int N = in_sizes[2] / D;

  float* outH = (float*)d_out;
  float* outE = outH + (size_t)N * D;

  // workspace carve-out (256B aligned)
  char* w = (char*)d_ws;
  auto alloc = [&](size_t bytes) -> void* {
    void* p = (void*)w;
    w += (bytes + 255) & ~(size_t)255;
    return p;
  };
  int*      deg_out  = (int*)alloc((size_t)N * 4);
  int*      cursor   = (int*)alloc((size_t)N * 4);
  float*    norm_src = (float*)alloc((size_t)N * 4);
  float*    norm_dst = (float*)alloc((size_t)N * 4);
  int*      ovf_cnt  = (int*)alloc(256);
  int2*     ovf      = (int2*)alloc((size_t)OVF_CAP * 8);
  int*      bucket   = (int*)alloc((size_t)N * CAP * 4);
  float*    agg      = (float*)alloc((size_t)N * D * 4);
  unsigned* xs       = (unsigned*)alloc((size_t)N * 64 * 4);   // bf16 x*ns
  unsigned* h1p      = (unsigned*)alloc((size_t)N * 64 * 4);   // bf16 h1*ns

  int nbN = (N + 255) / 256;
  int nbE = (E + 255) / 256;

  k_init<<<nbN, 256, 0, stream>>>(deg_out, cursor, ovf_cnt, N);
  k_fill<<<nbE, 256, 0, stream>>>(src, dst, deg_out, cursor, bucket, ovf_cnt, ovf, E);
  k_norm<<<nbN, 256, 0, stream>>>(deg_out, cursor, norm_src, norm_dst, N);

  // layer 1: xs = bf16(x*ns); agg1 = gather(xs); h1p = bf16(relu((agg1@W1)*nd+b1)*ns)
  k_prep<<<(N * 16 + 255) / 256, 256, 0, stream>>>(x, norm_src, (uint4*)xs, N * 16);
  k_agg_b<<<(N + 7) / 8, 256, 0, stream>>>(xs, cursor, bucket, agg, N);
  k_ovf_b<<<64, 128, 0, stream>>>(xs, ovf_cnt, ovf, agg);
  k_gemm_relu<<<(N + 63) / 64, 256, 0, stream>>>(agg, norm_dst, W1, b1, norm_src,
                                                 nullptr, h1p, N);

  // layer 2: agg2 = gather(h1p); h2 = relu((agg2@W2)*nd+b2) -> outH (f32)
  k_agg_b<<<(N + 7) / 8, 256, 0, stream>>>(h1p, cursor, bucket, agg, N);
  k_ovf_b<<<64, 128, 0, stream>>>(h1p, ovf_cnt, ovf, agg);
  k_gemm_relu<<<(N + 63) / 64, 256, 0, stream>>>(agg, norm_dst, W2, b2, nullptr,
                                                 outH, nullptr, N);

  // edge features
  int ntot = E + N;
  int nTiles = (ntot + 63) / 64;
  k_rel<<<nTiles, 256, 0, stream>>>(text, relW, relb, outE, E, ntot);
}